// Round 21
// baseline (259.702 us; speedup 1.0000x reference)
//
#include <hip/hip_runtime.h>

constexpr int B = 64, N = 1500, NT = B * N;
constexpr int E_PER = 24000;
constexpr int E_PAD = 34560; // per-graph ushort CSR capacity, rows padded to 8 (24000+7*1500=34500)
constexpr int F_INN = 128, K = 30, TOT = 97;

// ---- megakernel: one 1024-thread block per graph runs the whole GNN body ----
// P0 CSR build (ushort local idx, pad-8, pad = own index; scale=1+dc-pc corrects)
// P1 tA = nf_g @ W1 (12 tiles of 128 nodes, 4 concurrent 256-thread sub-tiles)
// P2 hc1 = tanh((gather(tA)+self+b1)/deg); tB = hc1 @ W2
// P3 hc2 = tanh((gather(tB)+self+b2)/deg); tA = hc2 @ W3
// P4 hc3 = tanh((gather(tA)+self+b3)/deg); t4 = hc3 . W4
// All sync is block-local; graph data stays in the block's XCD L2.
__global__ __launch_bounds__(1024) void mega(const int* __restrict__ src, const int* __restrict__ dst,
                                             const float* __restrict__ nf,
                                             const float* __restrict__ W1, const float* __restrict__ b1,
                                             const float* __restrict__ W2, const float* __restrict__ b2,
                                             const float* __restrict__ W3, const float* __restrict__ b3,
                                             const float* __restrict__ W4,
                                             ushort* __restrict__ csr, int* __restrict__ rowst,
                                             int* __restrict__ degi, float* __restrict__ degf,
                                             float* __restrict__ tA, float* __restrict__ tB,
                                             float* __restrict__ hc1, float* __restrict__ hc2,
                                             float* __restrict__ hc3, float* __restrict__ t4) {
    __shared__ union {
        struct { int hist[N]; uint4 slice[E_PAD / 8]; int wsum[4]; } c; // ~75.1 KB
        struct { float hs[4][32][128]; float Ws[32][32]; } g;           // 69.6 KB
        struct { float Wn[1024]; float outs[128][32]; } a;              // 20.5 KB
    } u;
    int g = blockIdx.x, t = threadIdx.x;
    int gbase = g * N;

    // ---------------- P0: CSR build ----------------
    {
        ushort* csr_l = (ushort*)u.c.slice;
        const int* dstg = dst + (size_t)g * E_PER;
        const int* srcg = src + (size_t)g * E_PER;
        for (int i = t; i < N; i += 1024) u.c.hist[i] = 0;
        __syncthreads();
        for (int e = t; e < E_PER; e += 1024)
            atomicAdd(&u.c.hist[dstg[e] - gbase], 1);
        __syncthreads();
        int local[6];
        int sum = 0, x = 0;
        if (t < 256) {
#pragma unroll
            for (int i = 0; i < 6; ++i) {
                int v = t * 6 + i;
                int d = (v < N) ? u.c.hist[v] : 0;
                local[i] = d;
                sum += (d + 7) & ~7;
            }
            x = sum;
            int lane = t & 63;
#pragma unroll
            for (int m = 1; m < 64; m <<= 1) {
                int y = __shfl_up(x, m, 64);
                if (lane >= m) x += y;
            }
            if (lane == 63) u.c.wsum[t >> 6] = x;
        }
        __syncthreads();
        if (t < 256) {
            int woff = 0;
            int wv = t >> 6;
            for (int w = 0; w < wv; ++w) woff += u.c.wsum[w];
            int run = x - sum + woff;
#pragma unroll
            for (int i = 0; i < 6; ++i) {
                int v = t * 6 + i;
                if (v < N) {
                    rowst[gbase + v] = g * E_PAD + run;
                    degi[gbase + v] = local[i];
                    degf[gbase + v] = (float)(local[i] + 1);
                    u.c.hist[v] = run;
                    run += (local[i] + 7) & ~7;
                }
            }
        }
        __syncthreads();
        for (int e = t; e < E_PER; e += 1024) {
            int d = dstg[e] - gbase;
            int pos = atomicAdd(&u.c.hist[d], 1);
            csr_l[pos] = (ushort)(srcg[e] - gbase);
        }
        __syncthreads();
        for (int v = t; v < N; v += 1024)
            for (int s = u.c.hist[v]; s & 7; ++s) csr_l[s] = (ushort)v;
        __syncthreads();
        uint4* cg = reinterpret_cast<uint4*>(csr + (size_t)g * E_PAD);
        for (int i = t; i < E_PAD / 8; i += 1024)
            cg[i] = u.c.slice[i];
    }
    __syncthreads();

    // ---------------- P1: tA = nf_g @ W1 ----------------
    {
        int sub = t >> 8, tid = t & 255;
        int wv = tid >> 6, lane = tid & 63;
        int og = wv * 8;
        for (int it = 0; it < 3; ++it) {
            int tile = it * 4 + sub;
            int v0 = tile * 128;
            float acc[2][8];
#pragma unroll
            for (int i = 0; i < 2; ++i)
#pragma unroll
                for (int j = 0; j < 8; ++j) acc[i][j] = 0.f;
            for (int kc = 0; kc < F_INN; kc += 32) {
                __syncthreads();
                {
                    int n = tid >> 1, kh = (tid & 1) * 16;
                    int row = gbase + min(v0 + n, N - 1);
                    const float4* hp4 = reinterpret_cast<const float4*>(nf + (size_t)row * F_INN + kc + kh);
                    float4 a = hp4[0], b = hp4[1], c = hp4[2], d = hp4[3];
                    float (*hs)[128] = u.g.hs[sub];
                    hs[kh + 0][n] = a.x;  hs[kh + 1][n] = a.y;  hs[kh + 2][n] = a.z;  hs[kh + 3][n] = a.w;
                    hs[kh + 4][n] = b.x;  hs[kh + 5][n] = b.y;  hs[kh + 6][n] = b.z;  hs[kh + 7][n] = b.w;
                    hs[kh + 8][n] = c.x;  hs[kh + 9][n] = c.y;  hs[kh + 10][n] = c.z; hs[kh + 11][n] = c.w;
                    hs[kh + 12][n] = d.x; hs[kh + 13][n] = d.y; hs[kh + 14][n] = d.z; hs[kh + 15][n] = d.w;
                }
                if (sub == 0) {
                    int r = tid >> 3, c4 = (tid & 7) * 4;
                    float4 w = *reinterpret_cast<const float4*>(W1 + (size_t)(kc + r) * 32 + c4);
                    *reinterpret_cast<float4*>(&u.g.Ws[r][c4]) = w;
                }
                __syncthreads();
#pragma unroll
                for (int k = 0; k < 32; ++k) {
                    float2 hv = *reinterpret_cast<const float2*>(&u.g.hs[sub][k][2 * lane]);
                    float4 w0 = *reinterpret_cast<const float4*>(&u.g.Ws[k][og]);
                    float4 w1 = *reinterpret_cast<const float4*>(&u.g.Ws[k][og + 4]);
                    acc[0][0] += hv.x * w0.x; acc[0][1] += hv.x * w0.y; acc[0][2] += hv.x * w0.z; acc[0][3] += hv.x * w0.w;
                    acc[0][4] += hv.x * w1.x; acc[0][5] += hv.x * w1.y; acc[0][6] += hv.x * w1.z; acc[0][7] += hv.x * w1.w;
                    acc[1][0] += hv.y * w0.x; acc[1][1] += hv.y * w0.y; acc[1][2] += hv.y * w0.z; acc[1][3] += hv.y * w0.w;
                    acc[1][4] += hv.y * w1.x; acc[1][5] += hv.y * w1.y; acc[1][6] += hv.y * w1.z; acc[1][7] += hv.y * w1.w;
                }
            }
#pragma unroll
            for (int i = 0; i < 2; ++i) {
                int vl = v0 + 2 * lane + i;
                if (vl < N) {
                    float* op = tA + (size_t)(gbase + vl) * 32 + og;
                    float4 r0 = {acc[i][0], acc[i][1], acc[i][2], acc[i][3]};
                    float4 r1 = {acc[i][4], acc[i][5], acc[i][6], acc[i][7]};
                    reinterpret_cast<float4*>(op)[0] = r0;
                    reinterpret_cast<float4*>(op)[1] = r1;
                }
            }
        }
    }
    __syncthreads();

    // ---------------- P2..P4: aggregate layers ----------------
    int gb8 = gbase * 8;
    int nl = t >> 3, f4 = t & 7;
    const ushort* csrg = csr; // global csr (L2-hot)

#define AGG_LAYER(TIN, BIASP, HOUT, DO_W4, WNEXT, TOUT)                                            \
    {                                                                                              \
        if (!(DO_W4)) {                                                                            \
            if (t < 1024) u.a.Wn[t] = (WNEXT)[t];                                                  \
            __syncthreads();                                                                       \
        }                                                                                          \
        const float4* t4v = reinterpret_cast<const float4*>(TIN);                                  \
        float4 bv = *reinterpret_cast<const float4*>((BIASP) + f4 * 4);                            \
        for (int it = 0; it < 12; ++it) {                                                          \
            int vl = it * 128 + nl;                                                                \
            if (vl < N) {                                                                          \
                int v = gbase + vl;                                                                \
                float4 tself = t4v[(unsigned)(v * 8 + f4)];                                        \
                int e0 = rowst[v];                                                                 \
                int dc = degi[v];                                                                  \
                int pc = (dc + 7) & ~7;                                                            \
                float scale = (float)(1 + dc - pc);                                                \
                float4 acc = {scale * tself.x, scale * tself.y, scale * tself.z, scale * tself.w}; \
                float4 s1 = {0, 0, 0, 0}, s2 = {0, 0, 0, 0}, s3 = {0, 0, 0, 0}, s4v = {0, 0, 0, 0};\
                for (int e = 0; e < pc; e += 8) {                                                  \
                    ushort4 ia = *reinterpret_cast<const ushort4*>(csrg + e0 + e);                 \
                    ushort4 ib = *reinterpret_cast<const ushort4*>(csrg + e0 + e + 4);             \
                    float4 x0 = t4v[(unsigned)(gb8 + ia.x * 8 + f4)];                              \
                    float4 x1 = t4v[(unsigned)(gb8 + ia.y * 8 + f4)];                              \
                    float4 x2 = t4v[(unsigned)(gb8 + ia.z * 8 + f4)];                              \
                    float4 x3 = t4v[(unsigned)(gb8 + ia.w * 8 + f4)];                              \
                    float4 x4 = t4v[(unsigned)(gb8 + ib.x * 8 + f4)];                              \
                    float4 x5 = t4v[(unsigned)(gb8 + ib.y * 8 + f4)];                              \
                    float4 x6 = t4v[(unsigned)(gb8 + ib.z * 8 + f4)];                              \
                    float4 x7 = t4v[(unsigned)(gb8 + ib.w * 8 + f4)];                              \
                    s1.x += x0.x + x1.x; s1.y += x0.y + x1.y; s1.z += x0.z + x1.z; s1.w += x0.w + x1.w; \
                    s2.x += x2.x + x3.x; s2.y += x2.y + x3.y; s2.z += x2.z + x3.z; s2.w += x2.w + x3.w; \
                    s3.x += x4.x + x5.x; s3.y += x4.y + x5.y; s3.z += x4.z + x5.z; s3.w += x4.w + x5.w; \
                    s4v.x += x6.x + x7.x; s4v.y += x6.y + x7.y; s4v.z += x6.z + x7.z; s4v.w += x6.w + x7.w; \
                }                                                                                  \
                acc.x += (s1.x + s2.x) + (s3.x + s4v.x);                                           \
                acc.y += (s1.y + s2.y) + (s3.y + s4v.y);                                           \
                acc.z += (s1.z + s2.z) + (s3.z + s4v.z);                                           \
                acc.w += (s1.w + s2.w) + (s3.w + s4v.w);                                           \
                float inv = 1.0f / degf[v];                                                        \
                float4 out;                                                                        \
                out.x = tanhf((acc.x + bv.x) * inv);                                               \
                out.y = tanhf((acc.y + bv.y) * inv);                                               \
                out.z = tanhf((acc.z + bv.z) * inv);                                               \
                out.w = tanhf((acc.w + bv.w) * inv);                                               \
                reinterpret_cast<float4*>(HOUT)[(unsigned)(v * 8 + f4)] = out;                     \
                if (DO_W4) {                                                                       \
                    float4 w4 = *reinterpret_cast<const float4*>(W4 + f4 * 4);                     \
                    float p = out.x * w4.x + out.y * w4.y + out.z * w4.z + out.w * w4.w;           \
                    p += __shfl_xor(p, 4, 64);                                                     \
                    p += __shfl_xor(p, 2, 64);                                                     \
                    p += __shfl_xor(p, 1, 64);                                                     \
                    if (f4 == 0) (TOUT)[v] = p;                                                    \
                } else {                                                                           \
                    *reinterpret_cast<float4*>(&u.a.outs[nl][f4 * 4]) = out;                       \
                    float4 s = {0, 0, 0, 0};                                                       \
                    _Pragma("unroll")                                                              \
                    for (int ff = 0; ff < 32; ++ff) {                                              \
                        float h = u.a.outs[nl][ff];                                                \
                        float4 wr = *reinterpret_cast<const float4*>(&u.a.Wn[ff * 32 + f4 * 4]);   \
                        s.x += h * wr.x; s.y += h * wr.y; s.z += h * wr.z; s.w += h * wr.w;        \
                    }                                                                              \
                    reinterpret_cast<float4*>(TOUT)[(unsigned)(v * 8 + f4)] = s;                   \
                }                                                                                  \
            }                                                                                      \
        }                                                                                          \
    }                                                                                              \
    __syncthreads();

    AGG_LAYER(tA, b1, hc1, false, W2, tB)
    AGG_LAYER(tB, b2, hc2, false, W3, tA)
    AGG_LAYER(tA, b3, hc3, true, W4, t4)
#undef AGG_LAYER
}

// -------- Fused layer4-agg + sortpool (radix top-K) + head: 512 thr/graph -----
__global__ __launch_bounds__(512) void sort_head(const float* __restrict__ hc1, const float* __restrict__ hc2,
                                                 const float* __restrict__ hc3, const float* __restrict__ t4,
                                                 const ushort* __restrict__ csr, const int* __restrict__ rowst,
                                                 const int* __restrict__ degi, const float* __restrict__ degf,
                                                 const float* __restrict__ b4,
                                                 const float* __restrict__ c1w, const float* __restrict__ c1b,
                                                 const float* __restrict__ c2w, const float* __restrict__ c2b,
                                                 const float* __restrict__ ow, const float* __restrict__ ob,
                                                 float* __restrict__ out) {
    __shared__ float ts[N];
    __shared__ unsigned int svals[N];
    __shared__ float fvals[N];
    __shared__ int hist[2048];
    __shared__ int canA[N], canB[N];
    __shared__ int winners[32];
    __shared__ int wsum[8];
    __shared__ int st_need, st_ncand, st_tb, st_cab, st_nwin;
    __shared__ int topk_s[K];
    __shared__ float pooled[K][TOT];
    __shared__ float c1[16][K];
    __shared__ float mp[16][16];
    __shared__ float dense[352];
    __shared__ float part[4][128];

    int g = blockIdx.x, t = threadIdx.x;
    int gbase = g * N;
    int lane = t & 63, w = t >> 6;

    for (int v = t; v < N; v += 512) ts[v] = t4[gbase + v];
    if (t == 0) { st_need = K; st_nwin = 0; }
    __syncthreads();
    {
        float b4v = b4[0];
        for (int v = t; v < N; v += 512) {
            int gv = gbase + v;
            int e0 = rowst[gv], dc = degi[gv];
            int pc = (dc + 7) & ~7;
            float scale = (float)(1 + dc - pc);
            float a0 = 0.f, a1 = 0.f, a2 = 0.f, a3 = 0.f;
            for (int e = 0; e < pc; e += 4) {
                ushort4 s4 = *reinterpret_cast<const ushort4*>(csr + e0 + e);
                a0 += ts[s4.x];
                a1 += ts[s4.y];
                a2 += ts[s4.z];
                a3 += ts[s4.w];
            }
            float h = tanhf((scale * ts[v] + (a0 + a1) + (a2 + a3) + b4v) / degf[gv]);
            fvals[v] = h;
            unsigned int b = __float_as_uint(h);
            svals[v] = (b & 0x80000000u) ? ~b : (b | 0x80000000u);
        }
    }
    __syncthreads();

    auto mkkey = [&](int idx) {
        return ((unsigned long long)svals[idx] << 31) | (unsigned int)(0x7FFFFFFF - idx);
    };

    const int SHIFTS[6] = {52, 41, 30, 19, 8, 0};
    int curN = N;
    int src = 0;
    for (int pass = 0; pass < 6; ++pass) {
        int shift = SHIFTS[pass];
        int mask = (pass == 5) ? 0xFF : 0x7FF;
        for (int i = t; i < 2048; i += 512) hist[i] = 0;
        if (t == 0) st_ncand = 0;
        __syncthreads();
        for (int i = t; i < curN; i += 512) {
            int idx = (src == 0) ? i : (src == 1 ? canA[i] : canB[i]);
            int d = (int)((mkkey(idx) >> shift) & mask);
            atomicAdd(&hist[d], 1);
        }
        __syncthreads();
        int need = st_need;
        int c[4];
        int s = 0;
#pragma unroll
        for (int u = 0; u < 4; ++u) { c[u] = hist[2047 - (4 * t + u)]; s += c[u]; }
        int x = s;
#pragma unroll
        for (int m = 1; m < 64; m <<= 1) {
            int y = __shfl_up(x, m, 64);
            if (lane >= m) x += y;
        }
        if (lane == 63) wsum[w] = x;
        __syncthreads();
        int woff = 0;
        for (int ww = 0; ww < w; ++ww) woff += wsum[ww];
        int A = woff + x - s;
#pragma unroll
        for (int u = 0; u < 4; ++u) {
            if (A < need && need <= A + c[u]) { st_tb = 2047 - (4 * t + u); st_cab = A; }
            A += c[u];
        }
        __syncthreads();
        int tb = st_tb, cab = st_cab;
        int* dst = (src == 1) ? canB : canA;
        for (int i = t; i < curN; i += 512) {
            int idx = (src == 0) ? i : (src == 1 ? canA[i] : canB[i]);
            int d = (int)((mkkey(idx) >> shift) & mask);
            if (d > tb) {
                int p = atomicAdd(&st_nwin, 1);
                winners[p] = idx;
            } else if (d == tb) {
                int p = atomicAdd(&st_ncand, 1);
                dst[p] = idx;
            }
        }
        __syncthreads();
        int ncand = st_ncand;
        need -= cab;
        if (t == 0) st_need = need;
        if (ncand == need) {
            int base = st_nwin;
            for (int i = t; i < ncand; i += 512) winners[base + i] = dst[i];
            __syncthreads();
            break;
        }
        curN = ncand;
        src = (src == 1) ? 2 : 1;
        __syncthreads();
    }

    if (t < 64) {
        unsigned long long key = (t < K) ? mkkey(winners[t]) : 0ull;
        unsigned long long kk = ~key;
#pragma unroll
        for (int k = 2; k <= 64; k <<= 1) {
#pragma unroll
            for (int j = k >> 1; j > 0; j >>= 1) {
                unsigned long long o = __shfl_xor(kk, j, 64);
                bool keepMin = ((t & j) == 0) == ((t & k) == 0);
                kk = keepMin ? (kk < o ? kk : o) : (kk > o ? kk : o);
            }
        }
        key = ~kk;
        if (t < K) topk_s[t] = 0x7FFFFFFF - (int)(unsigned int)(key & 0x7FFFFFFFu);
    }
    __syncthreads();

    for (int i = t; i < K * TOT; i += 512) {
        int k = i / TOT, d = i % TOT;
        int vloc = topk_s[k];
        int gi = gbase + vloc;
        float val = (d < 32) ? hc1[(size_t)gi * 32 + d]
                  : (d < 64) ? hc2[(size_t)gi * 32 + d - 32]
                  : (d < 96) ? hc3[(size_t)gi * 32 + d - 64]
                             : fvals[vloc];
        pooled[k][d] = val;
    }
    __syncthreads();
    for (int i = t; i < 16 * K; i += 512) {
        int o = i / K, k = i % K;
        float s = c1b[o];
        for (int d = 0; d < TOT; ++d) s += pooled[k][d] * c1w[o * TOT + d];
        c1[o][k] = fmaxf(s, 0.f);
    }
    __syncthreads();
    for (int i = t; i < 16 * 15; i += 512) {
        int o = i / 15, p = i % 15;
        mp[o][p] = fmaxf(c1[o][2 * p], c1[o][2 * p + 1]);
    }
    __syncthreads();
    for (int i = t; i < 352; i += 512) {
        int o = i / 11, p = i % 11;
        float s = c2b[o];
#pragma unroll
        for (int ci = 0; ci < 16; ++ci)
#pragma unroll
            for (int tt = 0; tt < 5; ++tt)
                s += mp[ci][p + tt] * c2w[(o * 16 + ci) * 5 + tt];
        dense[i] = fmaxf(s, 0.f);
    }
    __syncthreads();
    {
        int o = t & 127, q = t >> 7;
        float s = 0.f;
        for (int m = q * 88; m < (q + 1) * 88; ++m) s += dense[m] * ow[m * 128 + o];
        part[q][o] = s;
    }
    __syncthreads();
    if (t < 128) {
        float s = (part[0][t] + part[1][t]) + (part[2][t] + part[3][t]) + ob[t];
        out[g * 128 + t] = fmaxf(s, 0.f);
    }
}

extern "C" void kernel_launch(void* const* d_in, const int* in_sizes, int n_in,
                              void* d_out, int out_size, void* d_ws, size_t ws_size,
                              hipStream_t stream) {
    const float* node_feat = (const float*)d_in[0];
    const int* esrc = (const int*)d_in[1];
    const int* edst = (const int*)d_in[2];
    const float* W1 = (const float*)d_in[3];
    const float* b1 = (const float*)d_in[4];
    const float* W2 = (const float*)d_in[5];
    const float* b2 = (const float*)d_in[6];
    const float* W3 = (const float*)d_in[7];
    const float* b3 = (const float*)d_in[8];
    const float* W4 = (const float*)d_in[9];
    const float* b4 = (const float*)d_in[10];
    const float* c1w = (const float*)d_in[11];
    const float* c1b = (const float*)d_in[12];
    const float* c2w = (const float*)d_in[13];
    const float* c2b = (const float*)d_in[14];
    const float* ow = (const float*)d_in[15];
    const float* ob = (const float*)d_in[16];

    char* ws = (char*)d_ws;
    size_t off = 0;
    auto alloc = [&](size_t bytes) {
        size_t r = off;
        off += (bytes + 255) & ~(size_t)255;
        return r;
    };
    int* deg_i = (int*)(ws + alloc((size_t)NT * 4));
    int* rowst = (int*)(ws + alloc((size_t)NT * 4));
    float* degf = (float*)(ws + alloc((size_t)NT * 4));
    ushort* csr = (ushort*)(ws + alloc((size_t)B * E_PAD * 2));
    float* tA = (float*)(ws + alloc((size_t)NT * 32 * 4));
    float* tB = (float*)(ws + alloc((size_t)NT * 32 * 4));
    float* hc1 = (float*)(ws + alloc((size_t)NT * 32 * 4));
    float* hc2 = (float*)(ws + alloc((size_t)NT * 32 * 4));
    float* hc3 = (float*)(ws + alloc((size_t)NT * 32 * 4));
    float* t4 = (float*)(ws + alloc((size_t)NT * 4));

    mega<<<B, 1024, 0, stream>>>(esrc, edst, node_feat, W1, b1, W2, b2, W3, b3, W4,
                                 csr, rowst, deg_i, degf, tA, tB, hc1, hc2, hc3, t4);

    sort_head<<<B, 512, 0, stream>>>(hc1, hc2, hc3, t4, csr, rowst, deg_i, degf, b4,
                                     c1w, c1b, c2w, c2b, ow, ob, (float*)d_out);
}

// Round 22
// 113.286 us; speedup vs baseline: 2.2924x; 2.2924x over previous
//
#include <hip/hip_runtime.h>

constexpr int B = 64, N = 1500, NT = B * N;
constexpr int E_PER = 24000, E_TOT = B * E_PER;
constexpr int NQ = 4, NPQ = N / NQ;  // 4 node-quarters per graph, 375 nodes each
constexpr int CAP = 9216;            // ushort CSR capacity per quarter (pad-8 rows)
constexpr int PERM_STRIDE = 384;     // perm slots per quarter (>= NPQ)
constexpr int F_INN = 128, K = 30, TOT = 97;
constexpr int NB_G = 48;             // blocks per graph in agg_f: 4 quarters x 12
constexpr int GEMM_TILES = NT / 128; // 750

// ------ prep: ONE grid of 256-thread blocks (~7 blocks/CU).
// Blocks [0, 256): CSR build, one (graph, node-quarter) each: ushort local
// indices, rows padded to 8, pad = own index (consumers correct via
// scale = 1+dc-pc). Also counting-sorts the quarter's nodes by degree into
// perm (agg_f processes nodes in this order -> uniform edge-loop lengths).
// Blocks [256, 1006): t[NT,32] = node_feat @ W1, one 128-node tile each.
__global__ __launch_bounds__(256) void prep(const int* __restrict__ src, const int* __restrict__ dst,
                                            ushort* __restrict__ csr, int* __restrict__ rowst,
                                            int* __restrict__ degi, float* __restrict__ degf,
                                            ushort* __restrict__ perm,
                                            float* __restrict__ tA,
                                            const float* __restrict__ nf, const float* __restrict__ W1) {
    __shared__ union {
        struct { int hist[NPQ]; uint4 slice[CAP / 8]; int wtot; int dh[64]; } c; // ~20.2 KB
        struct { float hs[32][128]; float Ws[32][32]; } g;                        // 20.5 KB
    } u;
    int bid = blockIdx.x, t = threadIdx.x;

    if (bid < B * NQ) { // ---------------- CSR build path (quarter) ----------------
        ushort* csr_l = (ushort*)u.c.slice;
        int g = bid >> 2, q = bid & 3;
        int gbase = g * N, qlo = q * NPQ;
        const int4* d4 = reinterpret_cast<const int4*>(dst + (size_t)g * E_PER);
        const int4* s4 = reinterpret_cast<const int4*>(src + (size_t)g * E_PER);

        for (int i = t; i < NPQ; i += 256) u.c.hist[i] = 0;
        if (t < 64) u.c.dh[t] = 0;
        __syncthreads();
        for (int i = t; i < E_PER / 4; i += 256) {
            int4 d = d4[i];
            int x0 = d.x - gbase - qlo, x1 = d.y - gbase - qlo;
            int x2 = d.z - gbase - qlo, x3 = d.w - gbase - qlo;
            if ((unsigned)x0 < (unsigned)NPQ) atomicAdd(&u.c.hist[x0], 1);
            if ((unsigned)x1 < (unsigned)NPQ) atomicAdd(&u.c.hist[x1], 1);
            if ((unsigned)x2 < (unsigned)NPQ) atomicAdd(&u.c.hist[x2], 1);
            if ((unsigned)x3 < (unsigned)NPQ) atomicAdd(&u.c.hist[x3], 1);
        }
        __syncthreads();

        // prefix scan over 375 pad-8 counts: threads 0..127 (2 waves), 3 each.
        // Also histogram degrees (64 buckets) for the counting sort.
        int local[3];
        int sum = 0, x = 0;
        if (t < 128) {
#pragma unroll
            for (int i = 0; i < 3; ++i) {
                int v = t * 3 + i;
                int d = (v < NPQ) ? u.c.hist[v] : 0;
                local[i] = d;
                sum += (d + 7) & ~7;
                if (v < NPQ) atomicAdd(&u.c.dh[min(d, 63)], 1);
            }
            x = sum;
            int lane = t & 63;
#pragma unroll
            for (int m = 1; m < 64; m <<= 1) {
                int y = __shfl_up(x, m, 64);
                if (lane >= m) x += y;
            }
        }
        if (t == 63) u.c.wtot = x;
        __syncthreads();
        int myDeg[3]; // stash degrees for the sort scatter
#pragma unroll
        for (int i = 0; i < 3; ++i) myDeg[i] = (t < 128) ? local[i] : 0;
        if (t < 128) {
            int base = (t >= 64) ? u.c.wtot : 0;
            int run = base + x - sum; // exclusive pad-8 prefix of this thread's chunk
            int rbase = (g * NQ + q) * CAP;
#pragma unroll
            for (int i = 0; i < 3; ++i) {
                int v = t * 3 + i;
                if (v < NPQ) {
                    int gv = gbase + qlo + v;
                    rowst[gv] = rbase + run;
                    degi[gv] = local[i];
                    degf[gv] = (float)(local[i] + 1);
                    u.c.hist[v] = run;
                    run += (local[i] + 7) & ~7;
                }
            }
        }
        __syncthreads();
        // exclusive prefix of the 64 degree buckets (one wave)
        if (t < 64) {
            int c = u.c.dh[t];
            int xx = c;
#pragma unroll
            for (int m = 1; m < 64; m <<= 1) {
                int y = __shfl_up(xx, m, 64);
                if (t >= m) xx += y;
            }
            u.c.dh[t] = xx - c;
        }
        __syncthreads();
        // counting-sort scatter: perm[pos] = local node index, degree-ascending
        if (t < 128) {
            ushort* pg = perm + (size_t)(g * NQ + q) * PERM_STRIDE;
#pragma unroll
            for (int i = 0; i < 3; ++i) {
                int v = t * 3 + i;
                if (v < NPQ) {
                    int pos = atomicAdd(&u.c.dh[min(myDeg[i], 63)], 1);
                    pg[pos] = (ushort)v;
                }
            }
        }
        // csr scatter
        for (int i = t; i < E_PER / 4; i += 256) {
            int4 d = d4[i];
            int4 s = s4[i];
            int x0 = d.x - gbase - qlo, x1 = d.y - gbase - qlo;
            int x2 = d.z - gbase - qlo, x3 = d.w - gbase - qlo;
            if ((unsigned)x0 < (unsigned)NPQ) { int p = atomicAdd(&u.c.hist[x0], 1); csr_l[p] = (ushort)(s.x - gbase); }
            if ((unsigned)x1 < (unsigned)NPQ) { int p = atomicAdd(&u.c.hist[x1], 1); csr_l[p] = (ushort)(s.y - gbase); }
            if ((unsigned)x2 < (unsigned)NPQ) { int p = atomicAdd(&u.c.hist[x2], 1); csr_l[p] = (ushort)(s.z - gbase); }
            if ((unsigned)x3 < (unsigned)NPQ) { int p = atomicAdd(&u.c.hist[x3], 1); csr_l[p] = (ushort)(s.w - gbase); }
        }
        __syncthreads();
        // fill pad slots with the row's own (graph-local) index
        for (int v = t; v < NPQ; v += 256)
            for (int sft = u.c.hist[v]; sft & 7; ++sft) csr_l[sft] = (ushort)(qlo + v);
        __syncthreads();
        uint4* cg = reinterpret_cast<uint4*>(csr + (size_t)(g * NQ + q) * CAP);
        for (int i = t; i < CAP / 8; i += 256)
            cg[i] = u.c.slice[i];
    } else { // ---------------- GEMM path: one 128-node tile per block ----------
        int tile = bid - B * NQ;
        int wv = t >> 6, lane = t & 63;
        int v0 = tile * 128;
        int og = wv * 8;
        float acc[2][8];
#pragma unroll
        for (int i = 0; i < 2; ++i)
#pragma unroll
            for (int j = 0; j < 8; ++j) acc[i][j] = 0.f;

        for (int kc = 0; kc < F_INN; kc += 32) {
            __syncthreads();
            {
                int n = t >> 1, kh = (t & 1) * 16;
                const float* hp = nf + (size_t)(v0 + n) * F_INN + kc + kh;
                const float4* hp4 = reinterpret_cast<const float4*>(hp);
                float4 a = hp4[0], b = hp4[1], c = hp4[2], d = hp4[3];
                u.g.hs[kh + 0][n] = a.x;  u.g.hs[kh + 1][n] = a.y;  u.g.hs[kh + 2][n] = a.z;  u.g.hs[kh + 3][n] = a.w;
                u.g.hs[kh + 4][n] = b.x;  u.g.hs[kh + 5][n] = b.y;  u.g.hs[kh + 6][n] = b.z;  u.g.hs[kh + 7][n] = b.w;
                u.g.hs[kh + 8][n] = c.x;  u.g.hs[kh + 9][n] = c.y;  u.g.hs[kh + 10][n] = c.z; u.g.hs[kh + 11][n] = c.w;
                u.g.hs[kh + 12][n] = d.x; u.g.hs[kh + 13][n] = d.y; u.g.hs[kh + 14][n] = d.z; u.g.hs[kh + 15][n] = d.w;
                int r = t >> 3, c4 = (t & 7) * 4;
                float4 w = *reinterpret_cast<const float4*>(W1 + (size_t)(kc + r) * 32 + c4);
                *reinterpret_cast<float4*>(&u.g.Ws[r][c4]) = w;
            }
            __syncthreads();
#pragma unroll
            for (int k = 0; k < 32; ++k) {
                float2 hv = *reinterpret_cast<const float2*>(&u.g.hs[k][2 * lane]);
                float4 w0 = *reinterpret_cast<const float4*>(&u.g.Ws[k][og]);
                float4 w1 = *reinterpret_cast<const float4*>(&u.g.Ws[k][og + 4]);
                acc[0][0] += hv.x * w0.x; acc[0][1] += hv.x * w0.y; acc[0][2] += hv.x * w0.z; acc[0][3] += hv.x * w0.w;
                acc[0][4] += hv.x * w1.x; acc[0][5] += hv.x * w1.y; acc[0][6] += hv.x * w1.z; acc[0][7] += hv.x * w1.w;
                acc[1][0] += hv.y * w0.x; acc[1][1] += hv.y * w0.y; acc[1][2] += hv.y * w0.z; acc[1][3] += hv.y * w0.w;
                acc[1][4] += hv.y * w1.x; acc[1][5] += hv.y * w1.y; acc[1][6] += hv.y * w1.z; acc[1][7] += hv.y * w1.w;
            }
        }
#pragma unroll
        for (int i = 0; i < 2; ++i) {
            float* op = tA + (size_t)(v0 + 2 * lane + i) * 32 + og;
            float4 r0 = {acc[i][0], acc[i][1], acc[i][2], acc[i][3]};
            float4 r1 = {acc[i][4], acc[i][5], acc[i][6], acc[i][7]};
            reinterpret_cast<float4*>(op)[0] = r0;
            reinterpret_cast<float4*>(op)[1] = r1;
        }
    }
}

// ---- Aggregate (float4 lanes, 8 lanes/node), rows padded to 8, nodes visited
// in degree-sorted order (perm) so each wave's 8 nodes have equal loop length.
// Fused next-layer transform; XCD-swizzled blocks. ----
template <int FUSE>
__global__ __launch_bounds__(256) void agg_f(const float* __restrict__ t,
                                             const ushort* __restrict__ csr, const int* __restrict__ rowst,
                                             const int* __restrict__ degi, const float* __restrict__ degf,
                                             const ushort* __restrict__ perm,
                                             const float* __restrict__ bias, const float* __restrict__ Wn,
                                             float* __restrict__ hout, float* __restrict__ tn) {
    __shared__ float Ws[1024];
    __shared__ float outs[32][32];
    if (FUSE == 32) {
        for (int i = threadIdx.x; i < 1024; i += 256) Ws[i] = Wn[i];
    }
    int bid = blockIdx.x;
    int xcd = bid & 7, j = bid >> 3;
    int g = xcd + 8 * (j / NB_G);
    int nb = j % NB_G;
    int q = nb / 12, slot = nb % 12;
    int nl = threadIdx.x >> 3; // node slot within block [0,32)
    int f4 = threadIdx.x & 7;  // float4 slot [0,8)
    int idx = slot * 32 + nl;
    bool valid = idx < NPQ;
    int vl = 0;
    if (valid) vl = q * NPQ + perm[(size_t)(g * NQ + q) * PERM_STRIDE + idx];
    int v = g * N + vl;
    int gb8 = g * N * 8;
    const float4* t4v = reinterpret_cast<const float4*>(t);
    float4 out = {0.f, 0.f, 0.f, 0.f};
    if (valid) {
        float4 tself = t4v[(unsigned)(v * 8 + f4)];
        int e0 = rowst[v];
        int dc = degi[v];
        int pc = (dc + 7) & ~7;
        float scale = (float)(1 + dc - pc); // pads gathered (pc-dc) copies of self
        float4 acc = {scale * tself.x, scale * tself.y, scale * tself.z, scale * tself.w};
        float4 s1 = {0.f, 0.f, 0.f, 0.f}, s2 = {0.f, 0.f, 0.f, 0.f};
        float4 s3 = {0.f, 0.f, 0.f, 0.f}, s4v = {0.f, 0.f, 0.f, 0.f};
        for (int e = 0; e < pc; e += 8) {
            ushort4 ia = *reinterpret_cast<const ushort4*>(csr + e0 + e);
            ushort4 ib = *reinterpret_cast<const ushort4*>(csr + e0 + e + 4);
            float4 x0 = t4v[(unsigned)(gb8 + ia.x * 8 + f4)];
            float4 x1 = t4v[(unsigned)(gb8 + ia.y * 8 + f4)];
            float4 x2 = t4v[(unsigned)(gb8 + ia.z * 8 + f4)];
            float4 x3 = t4v[(unsigned)(gb8 + ia.w * 8 + f4)];
            float4 x4 = t4v[(unsigned)(gb8 + ib.x * 8 + f4)];
            float4 x5 = t4v[(unsigned)(gb8 + ib.y * 8 + f4)];
            float4 x6 = t4v[(unsigned)(gb8 + ib.z * 8 + f4)];
            float4 x7 = t4v[(unsigned)(gb8 + ib.w * 8 + f4)];
            s1.x += x0.x + x1.x; s1.y += x0.y + x1.y; s1.z += x0.z + x1.z; s1.w += x0.w + x1.w;
            s2.x += x2.x + x3.x; s2.y += x2.y + x3.y; s2.z += x2.z + x3.z; s2.w += x2.w + x3.w;
            s3.x += x4.x + x5.x; s3.y += x4.y + x5.y; s3.z += x4.z + x5.z; s3.w += x4.w + x5.w;
            s4v.x += x6.x + x7.x; s4v.y += x6.y + x7.y; s4v.z += x6.z + x7.z; s4v.w += x6.w + x7.w;
        }
        acc.x += (s1.x + s2.x) + (s3.x + s4v.x);
        acc.y += (s1.y + s2.y) + (s3.y + s4v.y);
        acc.z += (s1.z + s2.z) + (s3.z + s4v.z);
        acc.w += (s1.w + s2.w) + (s3.w + s4v.w);
        float4 bv = *reinterpret_cast<const float4*>(bias + f4 * 4);
        float inv = 1.0f / degf[v];
        out.x = tanhf((acc.x + bv.x) * inv);
        out.y = tanhf((acc.y + bv.y) * inv);
        out.z = tanhf((acc.z + bv.z) * inv);
        out.w = tanhf((acc.w + bv.w) * inv);
        reinterpret_cast<float4*>(hout)[(unsigned)(v * 8 + f4)] = out;
    }
    if (FUSE == 32) {
        *reinterpret_cast<float4*>(&outs[nl][f4 * 4]) = out;
        __syncthreads();
        if (valid) {
            float4 s = {0.f, 0.f, 0.f, 0.f};
#pragma unroll
            for (int ff = 0; ff < 32; ++ff) {
                float h = outs[nl][ff];
                float4 wr = *reinterpret_cast<const float4*>(&Ws[ff * 32 + f4 * 4]);
                s.x += h * wr.x; s.y += h * wr.y; s.z += h * wr.z; s.w += h * wr.w;
            }
            reinterpret_cast<float4*>(tn)[(unsigned)(v * 8 + f4)] = s;
        }
    } else if (valid) {
        float4 w4 = *reinterpret_cast<const float4*>(Wn + f4 * 4);
        float p = out.x * w4.x + out.y * w4.y + out.z * w4.z + out.w * w4.w;
        p += __shfl_xor(p, 4, 64);
        p += __shfl_xor(p, 2, 64);
        p += __shfl_xor(p, 1, 64);
        if (f4 == 0) tn[v] = p;
    }
}

// -------- Fused layer4-agg + sortpool (radix top-K) + head: 512 thr/graph -----
__global__ __launch_bounds__(512) void sort_head(const float* __restrict__ hc1, const float* __restrict__ hc2,
                                                 const float* __restrict__ hc3, const float* __restrict__ t4,
                                                 const ushort* __restrict__ csr, const int* __restrict__ rowst,
                                                 const int* __restrict__ degi, const float* __restrict__ degf,
                                                 const float* __restrict__ b4,
                                                 const float* __restrict__ c1w, const float* __restrict__ c1b,
                                                 const float* __restrict__ c2w, const float* __restrict__ c2b,
                                                 const float* __restrict__ ow, const float* __restrict__ ob,
                                                 float* __restrict__ out) {
    __shared__ float ts[N];            // t4 slice
    __shared__ unsigned int svals[N];  // sortable key-high
    __shared__ float fvals[N];         // h4
    __shared__ int hist[2048];
    __shared__ int canA[N], canB[N];
    __shared__ int winners[32];
    __shared__ int wsum[8];
    __shared__ int st_need, st_ncand, st_tb, st_cab, st_nwin;
    __shared__ int topk_s[K];
    __shared__ float pooled[K][TOT];
    __shared__ float c1[16][K];
    __shared__ float mp[16][16];
    __shared__ float dense[352];
    __shared__ float part[4][128];

    int g = blockIdx.x, t = threadIdx.x;
    int gbase = g * N;
    int lane = t & 63, w = t >> 6;

    // ---- fused layer-4 aggregation from LDS (local ushort csr, self-pads) ----
    for (int v = t; v < N; v += 512) ts[v] = t4[gbase + v];
    if (t == 0) { st_need = K; st_nwin = 0; }
    __syncthreads();
    {
        float b4v = b4[0];
        for (int v = t; v < N; v += 512) {
            int gv = gbase + v;
            int e0 = rowst[gv], dc = degi[gv];
            int pc = (dc + 7) & ~7;
            float scale = (float)(1 + dc - pc);
            float a0 = 0.f, a1 = 0.f, a2 = 0.f, a3 = 0.f;
            for (int e = 0; e < pc; e += 4) {
                ushort4 s4 = *reinterpret_cast<const ushort4*>(csr + e0 + e);
                a0 += ts[s4.x];
                a1 += ts[s4.y];
                a2 += ts[s4.z];
                a3 += ts[s4.w];
            }
            float h = tanhf((scale * ts[v] + (a0 + a1) + (a2 + a3) + b4v) / degf[gv]);
            fvals[v] = h;
            unsigned int b = __float_as_uint(h);
            svals[v] = (b & 0x80000000u) ? ~b : (b | 0x80000000u);
        }
    }
    __syncthreads();

    auto mkkey = [&](int idx) {
        return ((unsigned long long)svals[idx] << 31) | (unsigned int)(0x7FFFFFFF - idx);
    };

    const int SHIFTS[6] = {52, 41, 30, 19, 8, 0};
    int curN = N;
    int src = 0; // 0: implicit [0,N), 1: canA, 2: canB
    for (int pass = 0; pass < 6; ++pass) {
        int shift = SHIFTS[pass];
        int mask = (pass == 5) ? 0xFF : 0x7FF;
        for (int i = t; i < 2048; i += 512) hist[i] = 0;
        if (t == 0) st_ncand = 0;
        __syncthreads();
        for (int i = t; i < curN; i += 512) {
            int idx = (src == 0) ? i : (src == 1 ? canA[i] : canB[i]);
            int d = (int)((mkkey(idx) >> shift) & mask);
            atomicAdd(&hist[d], 1);
        }
        __syncthreads();
        int need = st_need;
        int c[4];
        int s = 0;
#pragma unroll
        for (int u = 0; u < 4; ++u) { c[u] = hist[2047 - (4 * t + u)]; s += c[u]; }
        int x = s;
#pragma unroll
        for (int m = 1; m < 64; m <<= 1) {
            int y = __shfl_up(x, m, 64);
            if (lane >= m) x += y;
        }
        if (lane == 63) wsum[w] = x;
        __syncthreads();
        int woff = 0;
        for (int ww = 0; ww < w; ++ww) woff += wsum[ww];
        int A = woff + x - s;
#pragma unroll
        for (int u = 0; u < 4; ++u) {
            if (A < need && need <= A + c[u]) { st_tb = 2047 - (4 * t + u); st_cab = A; }
            A += c[u];
        }
        __syncthreads();
        int tb = st_tb, cab = st_cab;
        int* dst = (src == 1) ? canB : canA;
        for (int i = t; i < curN; i += 512) {
            int idx = (src == 0) ? i : (src == 1 ? canA[i] : canB[i]);
            int d = (int)((mkkey(idx) >> shift) & mask);
            if (d > tb) {
                int p = atomicAdd(&st_nwin, 1);
                winners[p] = idx;
            } else if (d == tb) {
                int p = atomicAdd(&st_ncand, 1);
                dst[p] = idx;
            }
        }
        __syncthreads();
        int ncand = st_ncand;
        need -= cab;
        if (t == 0) st_need = need;
        if (ncand == need) {
            int base = st_nwin;
            for (int i = t; i < ncand; i += 512) winners[base + i] = dst[i];
            __syncthreads();
            break;
        }
        curN = ncand;
        src = (src == 1) ? 2 : 1;
        __syncthreads();
    }

    // exact ordering: bitonic sort of the 30 winner keys on wave 0
    if (t < 64) {
        unsigned long long key = (t < K) ? mkkey(winners[t]) : 0ull;
        unsigned long long kk = ~key;
#pragma unroll
        for (int k = 2; k <= 64; k <<= 1) {
#pragma unroll
            for (int j = k >> 1; j > 0; j >>= 1) {
                unsigned long long o = __shfl_xor(kk, j, 64);
                bool keepMin = ((t & j) == 0) == ((t & k) == 0);
                kk = keepMin ? (kk < o ? kk : o) : (kk > o ? kk : o);
            }
        }
        key = ~kk;
        if (t < K) topk_s[t] = 0x7FFFFFFF - (int)(unsigned int)(key & 0x7FFFFFFFu);
    }
    __syncthreads();

    for (int i = t; i < K * TOT; i += 512) {
        int k = i / TOT, d = i % TOT;
        int vloc = topk_s[k];
        int gi = gbase + vloc;
        float val = (d < 32) ? hc1[(size_t)gi * 32 + d]
                  : (d < 64) ? hc2[(size_t)gi * 32 + d - 32]
                  : (d < 96) ? hc3[(size_t)gi * 32 + d - 64]
                             : fvals[vloc];
        pooled[k][d] = val;
    }
    __syncthreads();
    for (int i = t; i < 16 * K; i += 512) {
        int o = i / K, k = i % K;
        float s = c1b[o];
        for (int d = 0; d < TOT; ++d) s += pooled[k][d] * c1w[o * TOT + d];
        c1[o][k] = fmaxf(s, 0.f);
    }
    __syncthreads();
    for (int i = t; i < 16 * 15; i += 512) {
        int o = i / 15, p = i % 15;
        mp[o][p] = fmaxf(c1[o][2 * p], c1[o][2 * p + 1]);
    }
    __syncthreads();
    for (int i = t; i < 352; i += 512) {
        int o = i / 11, p = i % 11;
        float s = c2b[o];
#pragma unroll
        for (int ci = 0; ci < 16; ++ci)
#pragma unroll
            for (int tt = 0; tt < 5; ++tt)
                s += mp[ci][p + tt] * c2w[(o * 16 + ci) * 5 + tt];
        dense[i] = fmaxf(s, 0.f);
    }
    __syncthreads();
    {
        int o = t & 127, q = t >> 7;
        float s = 0.f;
        for (int m = q * 88; m < (q + 1) * 88; ++m) s += dense[m] * ow[m * 128 + o];
        part[q][o] = s;
    }
    __syncthreads();
    if (t < 128) {
        float s = (part[0][t] + part[1][t]) + (part[2][t] + part[3][t]) + ob[t];
        out[g * 128 + t] = fmaxf(s, 0.f);
    }
}

extern "C" void kernel_launch(void* const* d_in, const int* in_sizes, int n_in,
                              void* d_out, int out_size, void* d_ws, size_t ws_size,
                              hipStream_t stream) {
    const float* node_feat = (const float*)d_in[0];
    const int* esrc = (const int*)d_in[1];
    const int* edst = (const int*)d_in[2];
    const float* W1 = (const float*)d_in[3];
    const float* b1 = (const float*)d_in[4];
    const float* W2 = (const float*)d_in[5];
    const float* b2 = (const float*)d_in[6];
    const float* W3 = (const float*)d_in[7];
    const float* b3 = (const float*)d_in[8];
    const float* W4 = (const float*)d_in[9];
    const float* b4 = (const float*)d_in[10];
    const float* c1w = (const float*)d_in[11];
    const float* c1b = (const float*)d_in[12];
    const float* c2w = (const float*)d_in[13];
    const float* c2b = (const float*)d_in[14];
    const float* ow = (const float*)d_in[15];
    const float* ob = (const float*)d_in[16];

    char* ws = (char*)d_ws;
    size_t off = 0;
    auto alloc = [&](size_t bytes) {
        size_t r = off;
        off += (bytes + 255) & ~(size_t)255;
        return r;
    };
    int* deg_i = (int*)(ws + alloc((size_t)NT * 4));
    int* rowst = (int*)(ws + alloc((size_t)NT * 4));
    float* degf = (float*)(ws + alloc((size_t)NT * 4));
    ushort* csr = (ushort*)(ws + alloc((size_t)B * NQ * CAP * 2));
    ushort* perm = (ushort*)(ws + alloc((size_t)B * NQ * PERM_STRIDE * 2));
    float* tA = (float*)(ws + alloc((size_t)NT * 32 * 4));
    float* tB = (float*)(ws + alloc((size_t)NT * 32 * 4));
    float* hc1 = (float*)(ws + alloc((size_t)NT * 32 * 4));
    float* hc2 = (float*)(ws + alloc((size_t)NT * 32 * 4));
    float* hc3 = (float*)(ws + alloc((size_t)NT * 32 * 4));
    float* t4 = (float*)(ws + alloc((size_t)NT * 4));

    prep<<<B * NQ + GEMM_TILES, 256, 0, stream>>>(esrc, edst, csr, rowst, deg_i, degf,
                                                  perm, tA, node_feat, W1);

    agg_f<32><<<8 * NB_G * 8, 256, 0, stream>>>(tA, csr, rowst, deg_i, degf, perm, b1, W2, hc1, tB);
    agg_f<32><<<8 * NB_G * 8, 256, 0, stream>>>(tB, csr, rowst, deg_i, degf, perm, b2, W3, hc2, tA);
    agg_f<1><<<8 * NB_G * 8, 256, 0, stream>>>(tA, csr, rowst, deg_i, degf, perm, b3, W4, hc3, t4);

    sort_head<<<B, 512, 0, stream>>>(hc1, hc2, hc3, t4, csr, rowst, deg_i, degf, b4,
                                     c1w, c1b, c2w, c2b, ow, ob, (float*)d_out);
}

// Round 23
// 105.096 us; speedup vs baseline: 2.4711x; 1.0779x over previous
//
#include <hip/hip_runtime.h>

constexpr int B = 64, N = 1500, NT = B * N;
constexpr int E_PER = 24000, E_TOT = B * E_PER;
constexpr int NQ = 4, NPQ = N / NQ;  // 4 node-quarters per graph, 375 nodes each
constexpr int CAP = 9216;            // ushort CSR capacity per quarter (pad-8 rows)
constexpr int PERM_STRIDE = 384;     // perm slots per quarter (>= NPQ)
constexpr int F_INN = 128, K = 30, TOT = 97;
constexpr int NB_G = 48;             // blocks per graph in agg_f: 4 quarters x 12
constexpr int GEMM_TILES = NT / 128; // 750
constexpr int GEMM_BLKS = GEMM_TILES / 2; // 375 (2 tiles per 512-thread block)

// ------ prep: ONE grid of 512-thread blocks.
// Blocks [0, 256): CSR build, one (graph, node-quarter) each: ushort local
// indices, rows padded to 8, pad = own index (consumers correct via
// scale = 1+dc-pc). Degree-counting-sort into perm. 512 threads halve the
// per-thread edge-pass length vs round-22.
// Blocks [256, 631): t[NT,32] = node_feat @ W1, TWO 128-node tiles per block.
__global__ __launch_bounds__(512) void prep(const int* __restrict__ src, const int* __restrict__ dst,
                                            ushort* __restrict__ csr, int* __restrict__ rowst,
                                            int* __restrict__ degi, float* __restrict__ degf,
                                            ushort* __restrict__ perm,
                                            float* __restrict__ tA,
                                            const float* __restrict__ nf, const float* __restrict__ W1) {
    __shared__ union {
        struct { int hist[NPQ]; uint4 slice[CAP / 8]; int wtot; int dh[64]; } c; // ~20.2 KB
        struct { float hs[2][32][128]; float Ws[32][32]; } g;                     // 36.9 KB
    } u;
    int bid = blockIdx.x, t = threadIdx.x;

    if (bid < B * NQ) { // ---------------- CSR build path (quarter) ----------------
        ushort* csr_l = (ushort*)u.c.slice;
        int g = bid >> 2, q = bid & 3;
        int gbase = g * N, qlo = q * NPQ;
        const int4* d4 = reinterpret_cast<const int4*>(dst + (size_t)g * E_PER);
        const int4* s4 = reinterpret_cast<const int4*>(src + (size_t)g * E_PER);

        for (int i = t; i < NPQ; i += 512) u.c.hist[i] = 0;
        if (t < 64) u.c.dh[t] = 0;
        __syncthreads();
        for (int i = t; i < E_PER / 4; i += 512) {
            int4 d = d4[i];
            int x0 = d.x - gbase - qlo, x1 = d.y - gbase - qlo;
            int x2 = d.z - gbase - qlo, x3 = d.w - gbase - qlo;
            if ((unsigned)x0 < (unsigned)NPQ) atomicAdd(&u.c.hist[x0], 1);
            if ((unsigned)x1 < (unsigned)NPQ) atomicAdd(&u.c.hist[x1], 1);
            if ((unsigned)x2 < (unsigned)NPQ) atomicAdd(&u.c.hist[x2], 1);
            if ((unsigned)x3 < (unsigned)NPQ) atomicAdd(&u.c.hist[x3], 1);
        }
        __syncthreads();

        // prefix scan over 375 pad-8 counts: threads 0..127 (2 waves), 3 each.
        // Also histogram degrees (64 buckets) for the counting sort.
        int local[3];
        int sum = 0, x = 0;
        if (t < 128) {
#pragma unroll
            for (int i = 0; i < 3; ++i) {
                int v = t * 3 + i;
                int d = (v < NPQ) ? u.c.hist[v] : 0;
                local[i] = d;
                sum += (d + 7) & ~7;
                if (v < NPQ) atomicAdd(&u.c.dh[min(d, 63)], 1);
            }
            x = sum;
            int lane = t & 63;
#pragma unroll
            for (int m = 1; m < 64; m <<= 1) {
                int y = __shfl_up(x, m, 64);
                if (lane >= m) x += y;
            }
        }
        if (t == 63) u.c.wtot = x;
        __syncthreads();
        int myDeg[3];
#pragma unroll
        for (int i = 0; i < 3; ++i) myDeg[i] = (t < 128) ? local[i] : 0;
        if (t < 128) {
            int base = (t >= 64) ? u.c.wtot : 0;
            int run = base + x - sum;
            int rbase = (g * NQ + q) * CAP;
#pragma unroll
            for (int i = 0; i < 3; ++i) {
                int v = t * 3 + i;
                if (v < NPQ) {
                    int gv = gbase + qlo + v;
                    rowst[gv] = rbase + run;
                    degi[gv] = local[i];
                    degf[gv] = (float)(local[i] + 1);
                    u.c.hist[v] = run;
                    run += (local[i] + 7) & ~7;
                }
            }
        }
        __syncthreads();
        // exclusive prefix of the 64 degree buckets (one wave)
        if (t < 64) {
            int c = u.c.dh[t];
            int xx = c;
#pragma unroll
            for (int m = 1; m < 64; m <<= 1) {
                int y = __shfl_up(xx, m, 64);
                if (t >= m) xx += y;
            }
            u.c.dh[t] = xx - c;
        }
        __syncthreads();
        // counting-sort scatter: perm[pos] = local node index, degree-ascending
        if (t < 128) {
            ushort* pg = perm + (size_t)(g * NQ + q) * PERM_STRIDE;
#pragma unroll
            for (int i = 0; i < 3; ++i) {
                int v = t * 3 + i;
                if (v < NPQ) {
                    int pos = atomicAdd(&u.c.dh[min(myDeg[i], 63)], 1);
                    pg[pos] = (ushort)v;
                }
            }
        }
        // csr scatter
        for (int i = t; i < E_PER / 4; i += 512) {
            int4 d = d4[i];
            int4 s = s4[i];
            int x0 = d.x - gbase - qlo, x1 = d.y - gbase - qlo;
            int x2 = d.z - gbase - qlo, x3 = d.w - gbase - qlo;
            if ((unsigned)x0 < (unsigned)NPQ) { int p = atomicAdd(&u.c.hist[x0], 1); csr_l[p] = (ushort)(s.x - gbase); }
            if ((unsigned)x1 < (unsigned)NPQ) { int p = atomicAdd(&u.c.hist[x1], 1); csr_l[p] = (ushort)(s.y - gbase); }
            if ((unsigned)x2 < (unsigned)NPQ) { int p = atomicAdd(&u.c.hist[x2], 1); csr_l[p] = (ushort)(s.z - gbase); }
            if ((unsigned)x3 < (unsigned)NPQ) { int p = atomicAdd(&u.c.hist[x3], 1); csr_l[p] = (ushort)(s.w - gbase); }
        }
        __syncthreads();
        // fill pad slots with the row's own (graph-local) index
        for (int v = t; v < NPQ; v += 512)
            for (int sft = u.c.hist[v]; sft & 7; ++sft) csr_l[sft] = (ushort)(qlo + v);
        __syncthreads();
        uint4* cg = reinterpret_cast<uint4*>(csr + (size_t)(g * NQ + q) * CAP);
        for (int i = t; i < CAP / 8; i += 512)
            cg[i] = u.c.slice[i];
    } else { // ------------- GEMM path: two 128-node tiles per 512-thr block -----
        int sub = t >> 8, tid = t & 255;
        int tile = (bid - B * NQ) * 2 + sub;
        int wv = tid >> 6, lane = tid & 63;
        int v0 = tile * 128;
        int og = wv * 8;
        float acc[2][8];
#pragma unroll
        for (int i = 0; i < 2; ++i)
#pragma unroll
            for (int j = 0; j < 8; ++j) acc[i][j] = 0.f;

        for (int kc = 0; kc < F_INN; kc += 32) {
            __syncthreads();
            {
                int n = tid >> 1, kh = (tid & 1) * 16;
                const float* hp = nf + (size_t)(v0 + n) * F_INN + kc + kh;
                const float4* hp4 = reinterpret_cast<const float4*>(hp);
                float4 a = hp4[0], b = hp4[1], c = hp4[2], d = hp4[3];
                float (*hs)[128] = u.g.hs[sub];
                hs[kh + 0][n] = a.x;  hs[kh + 1][n] = a.y;  hs[kh + 2][n] = a.z;  hs[kh + 3][n] = a.w;
                hs[kh + 4][n] = b.x;  hs[kh + 5][n] = b.y;  hs[kh + 6][n] = b.z;  hs[kh + 7][n] = b.w;
                hs[kh + 8][n] = c.x;  hs[kh + 9][n] = c.y;  hs[kh + 10][n] = c.z; hs[kh + 11][n] = c.w;
                hs[kh + 12][n] = d.x; hs[kh + 13][n] = d.y; hs[kh + 14][n] = d.z; hs[kh + 15][n] = d.w;
            }
            if (sub == 0) { // shared W chunk
                int r = tid >> 3, c4 = (tid & 7) * 4;
                float4 w = *reinterpret_cast<const float4*>(W1 + (size_t)(kc + r) * 32 + c4);
                *reinterpret_cast<float4*>(&u.g.Ws[r][c4]) = w;
            }
            __syncthreads();
#pragma unroll
            for (int k = 0; k < 32; ++k) {
                float2 hv = *reinterpret_cast<const float2*>(&u.g.hs[sub][k][2 * lane]);
                float4 w0 = *reinterpret_cast<const float4*>(&u.g.Ws[k][og]);
                float4 w1 = *reinterpret_cast<const float4*>(&u.g.Ws[k][og + 4]);
                acc[0][0] += hv.x * w0.x; acc[0][1] += hv.x * w0.y; acc[0][2] += hv.x * w0.z; acc[0][3] += hv.x * w0.w;
                acc[0][4] += hv.x * w1.x; acc[0][5] += hv.x * w1.y; acc[0][6] += hv.x * w1.z; acc[0][7] += hv.x * w1.w;
                acc[1][0] += hv.y * w0.x; acc[1][1] += hv.y * w0.y; acc[1][2] += hv.y * w0.z; acc[1][3] += hv.y * w0.w;
                acc[1][4] += hv.y * w1.x; acc[1][5] += hv.y * w1.y; acc[1][6] += hv.y * w1.z; acc[1][7] += hv.y * w1.w;
            }
        }
#pragma unroll
        for (int i = 0; i < 2; ++i) {
            float* op = tA + (size_t)(v0 + 2 * lane + i) * 32 + og;
            float4 r0 = {acc[i][0], acc[i][1], acc[i][2], acc[i][3]};
            float4 r1 = {acc[i][4], acc[i][5], acc[i][6], acc[i][7]};
            reinterpret_cast<float4*>(op)[0] = r0;
            reinterpret_cast<float4*>(op)[1] = r1;
        }
    }
}

// ---- Aggregate (float4 lanes, 8 lanes/node), rows padded to 8, nodes visited
// in degree-sorted order (perm) so each wave's 8 nodes have equal loop length.
// Fused next-layer transform; XCD-swizzled blocks. ----
template <int FUSE>
__global__ __launch_bounds__(256) void agg_f(const float* __restrict__ t,
                                             const ushort* __restrict__ csr, const int* __restrict__ rowst,
                                             const int* __restrict__ degi, const float* __restrict__ degf,
                                             const ushort* __restrict__ perm,
                                             const float* __restrict__ bias, const float* __restrict__ Wn,
                                             float* __restrict__ hout, float* __restrict__ tn) {
    __shared__ float Ws[1024];
    __shared__ float outs[32][32];
    if (FUSE == 32) {
        for (int i = threadIdx.x; i < 1024; i += 256) Ws[i] = Wn[i];
    }
    int bid = blockIdx.x;
    int xcd = bid & 7, j = bid >> 3;
    int g = xcd + 8 * (j / NB_G);
    int nb = j % NB_G;
    int q = nb / 12, slot = nb % 12;
    int nl = threadIdx.x >> 3; // node slot within block [0,32)
    int f4 = threadIdx.x & 7;  // float4 slot [0,8)
    int idx = slot * 32 + nl;
    bool valid = idx < NPQ;
    int vl = 0;
    if (valid) vl = q * NPQ + perm[(size_t)(g * NQ + q) * PERM_STRIDE + idx];
    int v = g * N + vl;
    int gb8 = g * N * 8;
    const float4* t4v = reinterpret_cast<const float4*>(t);
    float4 out = {0.f, 0.f, 0.f, 0.f};
    if (valid) {
        float4 tself = t4v[(unsigned)(v * 8 + f4)];
        int e0 = rowst[v];
        int dc = degi[v];
        int pc = (dc + 7) & ~7;
        float scale = (float)(1 + dc - pc); // pads gathered (pc-dc) copies of self
        float4 acc = {scale * tself.x, scale * tself.y, scale * tself.z, scale * tself.w};
        float4 s1 = {0.f, 0.f, 0.f, 0.f}, s2 = {0.f, 0.f, 0.f, 0.f};
        float4 s3 = {0.f, 0.f, 0.f, 0.f}, s4v = {0.f, 0.f, 0.f, 0.f};
        for (int e = 0; e < pc; e += 8) {
            ushort4 ia = *reinterpret_cast<const ushort4*>(csr + e0 + e);
            ushort4 ib = *reinterpret_cast<const ushort4*>(csr + e0 + e + 4);
            float4 x0 = t4v[(unsigned)(gb8 + ia.x * 8 + f4)];
            float4 x1 = t4v[(unsigned)(gb8 + ia.y * 8 + f4)];
            float4 x2 = t4v[(unsigned)(gb8 + ia.z * 8 + f4)];
            float4 x3 = t4v[(unsigned)(gb8 + ia.w * 8 + f4)];
            float4 x4 = t4v[(unsigned)(gb8 + ib.x * 8 + f4)];
            float4 x5 = t4v[(unsigned)(gb8 + ib.y * 8 + f4)];
            float4 x6 = t4v[(unsigned)(gb8 + ib.z * 8 + f4)];
            float4 x7 = t4v[(unsigned)(gb8 + ib.w * 8 + f4)];
            s1.x += x0.x + x1.x; s1.y += x0.y + x1.y; s1.z += x0.z + x1.z; s1.w += x0.w + x1.w;
            s2.x += x2.x + x3.x; s2.y += x2.y + x3.y; s2.z += x2.z + x3.z; s2.w += x2.w + x3.w;
            s3.x += x4.x + x5.x; s3.y += x4.y + x5.y; s3.z += x4.z + x5.z; s3.w += x4.w + x5.w;
            s4v.x += x6.x + x7.x; s4v.y += x6.y + x7.y; s4v.z += x6.z + x7.z; s4v.w += x6.w + x7.w;
        }
        acc.x += (s1.x + s2.x) + (s3.x + s4v.x);
        acc.y += (s1.y + s2.y) + (s3.y + s4v.y);
        acc.z += (s1.z + s2.z) + (s3.z + s4v.z);
        acc.w += (s1.w + s2.w) + (s3.w + s4v.w);
        float4 bv = *reinterpret_cast<const float4*>(bias + f4 * 4);
        float inv = 1.0f / degf[v];
        out.x = tanhf((acc.x + bv.x) * inv);
        out.y = tanhf((acc.y + bv.y) * inv);
        out.z = tanhf((acc.z + bv.z) * inv);
        out.w = tanhf((acc.w + bv.w) * inv);
        reinterpret_cast<float4*>(hout)[(unsigned)(v * 8 + f4)] = out;
    }
    if (FUSE == 32) {
        *reinterpret_cast<float4*>(&outs[nl][f4 * 4]) = out;
        __syncthreads();
        if (valid) {
            float4 s = {0.f, 0.f, 0.f, 0.f};
#pragma unroll
            for (int ff = 0; ff < 32; ++ff) {
                float h = outs[nl][ff];
                float4 wr = *reinterpret_cast<const float4*>(&Ws[ff * 32 + f4 * 4]);
                s.x += h * wr.x; s.y += h * wr.y; s.z += h * wr.z; s.w += h * wr.w;
            }
            reinterpret_cast<float4*>(tn)[(unsigned)(v * 8 + f4)] = s;
        }
    } else if (valid) {
        float4 w4 = *reinterpret_cast<const float4*>(Wn + f4 * 4);
        float p = out.x * w4.x + out.y * w4.y + out.z * w4.z + out.w * w4.w;
        p += __shfl_xor(p, 4, 64);
        p += __shfl_xor(p, 2, 64);
        p += __shfl_xor(p, 1, 64);
        if (f4 == 0) tn[v] = p;
    }
}

// -------- Fused layer4-agg + sortpool (radix top-K) + head: 512 thr/graph -----
__global__ __launch_bounds__(512) void sort_head(const float* __restrict__ hc1, const float* __restrict__ hc2,
                                                 const float* __restrict__ hc3, const float* __restrict__ t4,
                                                 const ushort* __restrict__ csr, const int* __restrict__ rowst,
                                                 const int* __restrict__ degi, const float* __restrict__ degf,
                                                 const float* __restrict__ b4,
                                                 const float* __restrict__ c1w, const float* __restrict__ c1b,
                                                 const float* __restrict__ c2w, const float* __restrict__ c2b,
                                                 const float* __restrict__ ow, const float* __restrict__ ob,
                                                 float* __restrict__ out) {
    __shared__ float ts[N];            // t4 slice
    __shared__ unsigned int svals[N];  // sortable key-high
    __shared__ float fvals[N];         // h4
    __shared__ int hist[2048];
    __shared__ int canA[N], canB[N];
    __shared__ int winners[32];
    __shared__ int wsum[8];
    __shared__ int st_need, st_ncand, st_tb, st_cab, st_nwin;
    __shared__ int topk_s[K];
    __shared__ float pooled[K][TOT];
    __shared__ float c1[16][K];
    __shared__ float mp[16][16];
    __shared__ float dense[352];
    __shared__ float part[4][128];

    int g = blockIdx.x, t = threadIdx.x;
    int gbase = g * N;
    int lane = t & 63, w = t >> 6;

    // ---- fused layer-4 aggregation from LDS (local ushort csr, self-pads) ----
    for (int v = t; v < N; v += 512) ts[v] = t4[gbase + v];
    if (t == 0) { st_need = K; st_nwin = 0; }
    __syncthreads();
    {
        float b4v = b4[0];
        for (int v = t; v < N; v += 512) {
            int gv = gbase + v;
            int e0 = rowst[gv], dc = degi[gv];
            int pc = (dc + 7) & ~7;
            float scale = (float)(1 + dc - pc);
            float a0 = 0.f, a1 = 0.f, a2 = 0.f, a3 = 0.f;
            for (int e = 0; e < pc; e += 4) {
                ushort4 s4 = *reinterpret_cast<const ushort4*>(csr + e0 + e);
                a0 += ts[s4.x];
                a1 += ts[s4.y];
                a2 += ts[s4.z];
                a3 += ts[s4.w];
            }
            float h = tanhf((scale * ts[v] + (a0 + a1) + (a2 + a3) + b4v) / degf[gv]);
            fvals[v] = h;
            unsigned int b = __float_as_uint(h);
            svals[v] = (b & 0x80000000u) ? ~b : (b | 0x80000000u);
        }
    }
    __syncthreads();

    auto mkkey = [&](int idx) {
        return ((unsigned long long)svals[idx] << 31) | (unsigned int)(0x7FFFFFFF - idx);
    };

    const int SHIFTS[6] = {52, 41, 30, 19, 8, 0};
    int curN = N;
    int src = 0; // 0: implicit [0,N), 1: canA, 2: canB
    for (int pass = 0; pass < 6; ++pass) {
        int shift = SHIFTS[pass];
        int mask = (pass == 5) ? 0xFF : 0x7FF;
        for (int i = t; i < 2048; i += 512) hist[i] = 0;
        if (t == 0) st_ncand = 0;
        __syncthreads();
        for (int i = t; i < curN; i += 512) {
            int idx = (src == 0) ? i : (src == 1 ? canA[i] : canB[i]);
            int d = (int)((mkkey(idx) >> shift) & mask);
            atomicAdd(&hist[d], 1);
        }
        __syncthreads();
        int need = st_need;
        int c[4];
        int s = 0;
#pragma unroll
        for (int u = 0; u < 4; ++u) { c[u] = hist[2047 - (4 * t + u)]; s += c[u]; }
        int x = s;
#pragma unroll
        for (int m = 1; m < 64; m <<= 1) {
            int y = __shfl_up(x, m, 64);
            if (lane >= m) x += y;
        }
        if (lane == 63) wsum[w] = x;
        __syncthreads();
        int woff = 0;
        for (int ww = 0; ww < w; ++ww) woff += wsum[ww];
        int A = woff + x - s;
#pragma unroll
        for (int u = 0; u < 4; ++u) {
            if (A < need && need <= A + c[u]) { st_tb = 2047 - (4 * t + u); st_cab = A; }
            A += c[u];
        }
        __syncthreads();
        int tb = st_tb, cab = st_cab;
        int* dst = (src == 1) ? canB : canA;
        for (int i = t; i < curN; i += 512) {
            int idx = (src == 0) ? i : (src == 1 ? canA[i] : canB[i]);
            int d = (int)((mkkey(idx) >> shift) & mask);
            if (d > tb) {
                int p = atomicAdd(&st_nwin, 1);
                winners[p] = idx;
            } else if (d == tb) {
                int p = atomicAdd(&st_ncand, 1);
                dst[p] = idx;
            }
        }
        __syncthreads();
        int ncand = st_ncand;
        need -= cab;
        if (t == 0) st_need = need;
        if (ncand == need) {
            int base = st_nwin;
            for (int i = t; i < ncand; i += 512) winners[base + i] = dst[i];
            __syncthreads();
            break;
        }
        curN = ncand;
        src = (src == 1) ? 2 : 1;
        __syncthreads();
    }

    // exact ordering: bitonic sort of the 30 winner keys on wave 0
    if (t < 64) {
        unsigned long long key = (t < K) ? mkkey(winners[t]) : 0ull;
        unsigned long long kk = ~key;
#pragma unroll
        for (int k = 2; k <= 64; k <<= 1) {
#pragma unroll
            for (int j = k >> 1; j > 0; j >>= 1) {
                unsigned long long o = __shfl_xor(kk, j, 64);
                bool keepMin = ((t & j) == 0) == ((t & k) == 0);
                kk = keepMin ? (kk < o ? kk : o) : (kk > o ? kk : o);
            }
        }
        key = ~kk;
        if (t < K) topk_s[t] = 0x7FFFFFFF - (int)(unsigned int)(key & 0x7FFFFFFFu);
    }
    __syncthreads();

    for (int i = t; i < K * TOT; i += 512) {
        int k = i / TOT, d = i % TOT;
        int vloc = topk_s[k];
        int gi = gbase + vloc;
        float val = (d < 32) ? hc1[(size_t)gi * 32 + d]
                  : (d < 64) ? hc2[(size_t)gi * 32 + d - 32]
                  : (d < 96) ? hc3[(size_t)gi * 32 + d - 64]
                             : fvals[vloc];
        pooled[k][d] = val;
    }
    __syncthreads();
    for (int i = t; i < 16 * K; i += 512) {
        int o = i / K, k = i % K;
        float s = c1b[o];
        for (int d = 0; d < TOT; ++d) s += pooled[k][d] * c1w[o * TOT + d];
        c1[o][k] = fmaxf(s, 0.f);
    }
    __syncthreads();
    for (int i = t; i < 16 * 15; i += 512) {
        int o = i / 15, p = i % 15;
        mp[o][p] = fmaxf(c1[o][2 * p], c1[o][2 * p + 1]);
    }
    __syncthreads();
    for (int i = t; i < 352; i += 512) {
        int o = i / 11, p = i % 11;
        float s = c2b[o];
#pragma unroll
        for (int ci = 0; ci < 16; ++ci)
#pragma unroll
            for (int tt = 0; tt < 5; ++tt)
                s += mp[ci][p + tt] * c2w[(o * 16 + ci) * 5 + tt];
        dense[i] = fmaxf(s, 0.f);
    }
    __syncthreads();
    {
        int o = t & 127, q = t >> 7;
        float s = 0.f;
        for (int m = q * 88; m < (q + 1) * 88; ++m) s += dense[m] * ow[m * 128 + o];
        part[q][o] = s;
    }
    __syncthreads();
    if (t < 128) {
        float s = (part[0][t] + part[1][t]) + (part[2][t] + part[3][t]) + ob[t];
        out[g * 128 + t] = fmaxf(s, 0.f);
    }
}

extern "C" void kernel_launch(void* const* d_in, const int* in_sizes, int n_in,
                              void* d_out, int out_size, void* d_ws, size_t ws_size,
                              hipStream_t stream) {
    const float* node_feat = (const float*)d_in[0];
    const int* esrc = (const int*)d_in[1];
    const int* edst = (const int*)d_in[2];
    const float* W1 = (const float*)d_in[3];
    const float* b1 = (const float*)d_in[4];
    const float* W2 = (const float*)d_in[5];
    const float* b2 = (const float*)d_in[6];
    const float* W3 = (const float*)d_in[7];
    const float* b3 = (const float*)d_in[8];
    const float* W4 = (const float*)d_in[9];
    const float* b4 = (const float*)d_in[10];
    const float* c1w = (const float*)d_in[11];
    const float* c1b = (const float*)d_in[12];
    const float* c2w = (const float*)d_in[13];
    const float* c2b = (const float*)d_in[14];
    const float* ow = (const float*)d_in[15];
    const float* ob = (const float*)d_in[16];

    char* ws = (char*)d_ws;
    size_t off = 0;
    auto alloc = [&](size_t bytes) {
        size_t r = off;
        off += (bytes + 255) & ~(size_t)255;
        return r;
    };
    int* deg_i = (int*)(ws + alloc((size_t)NT * 4));
    int* rowst = (int*)(ws + alloc((size_t)NT * 4));
    float* degf = (float*)(ws + alloc((size_t)NT * 4));
    ushort* csr = (ushort*)(ws + alloc((size_t)B * NQ * CAP * 2));
    ushort* perm = (ushort*)(ws + alloc((size_t)B * NQ * PERM_STRIDE * 2));
    float* tA = (float*)(ws + alloc((size_t)NT * 32 * 4));
    float* tB = (float*)(ws + alloc((size_t)NT * 32 * 4));
    float* hc1 = (float*)(ws + alloc((size_t)NT * 32 * 4));
    float* hc2 = (float*)(ws + alloc((size_t)NT * 32 * 4));
    float* hc3 = (float*)(ws + alloc((size_t)NT * 32 * 4));
    float* t4 = (float*)(ws + alloc((size_t)NT * 4));

    prep<<<B * NQ + GEMM_BLKS, 512, 0, stream>>>(esrc, edst, csr, rowst, deg_i, degf,
                                                 perm, tA, node_feat, W1);

    agg_f<32><<<8 * NB_G * 8, 256, 0, stream>>>(tA, csr, rowst, deg_i, degf, perm, b1, W2, hc1, tB);
    agg_f<32><<<8 * NB_G * 8, 256, 0, stream>>>(tB, csr, rowst, deg_i, degf, perm, b2, W3, hc2, tA);
    agg_f<1><<<8 * NB_G * 8, 256, 0, stream>>>(tA, csr, rowst, deg_i, degf, perm, b3, W4, hc3, t4);

    sort_head<<<B, 512, 0, stream>>>(hc1, hc2, hc3, t4, csr, rowst, deg_i, degf, b4,
                                     c1w, c1b, c2w, c2b, ow, ob, (float*)d_out);
}